// Round 12
// baseline (235.131 us; speedup 1.0000x reference)
//
#include <hip/hip_runtime.h>
#include <hip/hip_bf16.h>

#define B_ 8
#define T_ 1024
#define C_ 1024
#define H_ 16
#define D_ 64
#define QKVLD 3072  // [Q(1024) | K(1024) | V(unused)] ; col = part*1024 + h*64 + d

typedef short v4s __attribute__((ext_vector_type(4)));
typedef short v8s __attribute__((ext_vector_type(8)));
typedef float v4f __attribute__((ext_vector_type(4)));
typedef float v16f __attribute__((ext_vector_type(16)));

__device__ __forceinline__ unsigned short f2b(float f) {
    unsigned int u = __builtin_bit_cast(unsigned int, f);
    unsigned int lsb = (u >> 16) & 1u;
    u += 0x7fffu + lsb;
    return (unsigned short)(u >> 16);
}

__device__ __forceinline__ v4s pack4(float p0, float p1, float p2, float p3) {
    unsigned int a = (__builtin_bit_cast(unsigned int, p0) + 0x8000u) >> 16;
    unsigned int b = (__builtin_bit_cast(unsigned int, p1) + 0x8000u) & 0xFFFF0000u;
    unsigned int c = (__builtin_bit_cast(unsigned int, p2) + 0x8000u) >> 16;
    unsigned int d = (__builtin_bit_cast(unsigned int, p3) + 0x8000u) & 0xFFFF0000u;
    union { unsigned int u[2]; v4s v; } t;
    t.u[0] = a | b; t.u[1] = c | d;
    return t.v;
}

#define MFMA32(A, B, C) __builtin_amdgcn_mfma_f32_16x16x32_bf16(A, B, C, 0, 0, 0)
#define MFMA16(A, B, C) __builtin_amdgcn_mfma_f32_16x16x16bf16_1k(A, B, C, 0, 0, 0)

#define GLOAD16(gp, lp)                                                          \
    __builtin_amdgcn_global_load_lds(                                            \
        (const __attribute__((address_space(1))) unsigned int*)(gp),             \
        (__attribute__((address_space(3))) unsigned int*)(lp), 16, 0, 0)

// ---------------- fused prep: cast x + transpose Wqkv + transpose Wproj ----------------
__global__ void prep_kernel(const float* __restrict__ x, const float* __restrict__ Wq,
                            const float* __restrict__ Wk, const float* __restrict__ Wv,
                            const float* __restrict__ Wproj,
                            unsigned short* __restrict__ xb,
                            unsigned short* __restrict__ WqkvT,
                            unsigned short* __restrict__ WprojT) {
    __shared__ unsigned short t[64][65];
    int g = blockIdx.x;
    if (g < 8192) {
        int i = (g * 256 + (int)threadIdx.x) * 4;
        float4 v = *(const float4*)(x + i);
        ushort4 o;
        o.x = f2b(v.x); o.y = f2b(v.y); o.z = f2b(v.z); o.w = f2b(v.w);
        *(ushort4*)(xb + i) = o;
    } else if (g < 8192 + 768) {
        int idx = g - 8192;
        int z = idx >> 4;
        int h = z / 3, part = z % 3;
        const float* src = (part == 0 ? Wq : (part == 1 ? Wk : Wv)) + (size_t)h * C_ * D_;
        int c0 = (idx & 15) * 64;
        for (int i = threadIdx.x; i < 4096; i += 256) {
            int r = i >> 6, d = i & 63;
            t[d][r] = f2b(src[(size_t)(c0 + r) * D_ + d]);
        }
        __syncthreads();
        unsigned short* dst = WqkvT + (size_t)(part * 1024 + h * 64) * C_;
        for (int i = threadIdx.x; i < 4096; i += 256) {
            int d = i >> 6, r = i & 63;
            dst[(size_t)d * C_ + c0 + r] = t[d][r];
        }
    } else {
        int idx = g - 8960;
        int n0 = (idx & 15) * 64, k0 = (idx >> 4) * 64;
        for (int i = threadIdx.x; i < 4096; i += 256) {
            int r = i >> 6, c = i & 63;
            t[c][r] = f2b(Wproj[(size_t)(k0 + r) * C_ + n0 + c]);
        }
        __syncthreads();
        for (int i = threadIdx.x; i < 4096; i += 256) {
            int n = i >> 6, k = i & 63;
            WprojT[(size_t)(n0 + n) * 1024 + k0 + k] = t[n][k];
        }
    }
}

// ---------------- GEMM QK v4: R2-exact 256x128 2-stage drain body + XCD-stripe map ------
// N = 2048 (Q|K sections only). Output stride ldc = 3072 into the QKV buffer.
// K section (cols >= 1024) pre-scaled by 0.125 = D^-0.5 so attn softmax needs no scale.
// Grid 512 1-D. Map: xcd=g&7, s=g>>3, m0=(xcd*4+(s&3))*256, n0=(s>>2)*128 — each XCD owns
// a contiguous 4-panel m-stripe (2 MB A) + shared 4 MB B -> L2-resident, short drains.
__global__ __launch_bounds__(256, 2) void gemm_qk(const unsigned short* __restrict__ A,
                                                  const unsigned short* __restrict__ Bt,
                                                  unsigned short* __restrict__ Cout,
                                                  int K, int ldc) {
    constexpr int ABUF = 256 * 32;
    constexpr int BBUF = 128 * 32;
    __shared__ unsigned short smem[2 * ABUF + 2 * BBUF];   // 48 KB
    unsigned short* lA0 = smem;
    unsigned short* lB0 = smem + 2 * ABUF;

    int tid = threadIdx.x;
    int lane = tid & 63, w = tid >> 6;
    int half = lane >> 5, l32 = lane & 31;
    int wm = w >> 1, wn = w & 1;

    int g = blockIdx.x;
    int xcd = g & 7, s = g >> 3;
    int m0 = (xcd * 4 + (s & 3)) * 256;
    int n0 = (s >> 2) * 128;

    const unsigned short* gA[4];
    int offA[4];
    #pragma unroll
    for (int j = 0; j < 4; j++) {
        int c = j * 256 + tid;
        int row = c >> 2;
        int col8 = ((c & 3) ^ ((row >> 1) & 3)) * 8;
        gA[j] = A + (size_t)(m0 + row) * K + col8;
        offA[j] = (j * 256 + w * 64) * 16;
    }
    const unsigned short* gB[2];
    int offB[2];
    #pragma unroll
    for (int j = 0; j < 2; j++) {
        int c = j * 256 + tid;
        int row = c >> 2;
        int col8 = ((c & 3) ^ ((row >> 1) & 3)) * 8;
        gB[j] = Bt + (size_t)(n0 + row) * K + col8;
        offB[j] = (j * 256 + w * 64) * 16;
    }

    int am[4], bn[2];
    #pragma unroll
    for (int mi = 0; mi < 4; mi++) am[mi] = wm * 128 + mi * 32 + l32;
    #pragma unroll
    for (int ni = 0; ni < 2; ni++) bn[ni] = wn * 64 + ni * 32 + l32;

    v16f acc[4][2];
    #pragma unroll
    for (int mi = 0; mi < 4; mi++)
        #pragma unroll
        for (int ni = 0; ni < 2; ni++)
            #pragma unroll
            for (int r = 0; r < 16; r++) acc[mi][ni][r] = 0.f;

    int ktiles = K >> 5;
    #pragma unroll
    for (int j = 0; j < 4; j++) GLOAD16(gA[j], (char*)lA0 + offA[j]);
    #pragma unroll
    for (int j = 0; j < 2; j++) GLOAD16(gB[j], (char*)lB0 + offB[j]);

    for (int it = 0; it < ktiles; it++) {
        int cur = it & 1, nxt = cur ^ 1;
        __asm__ volatile("s_waitcnt vmcnt(0)" ::: "memory");
        __asm__ volatile("s_barrier" ::: "memory");
        {
            int kn = (it + 1 < ktiles) ? (it + 1) * 32 : it * 32;
            #pragma unroll
            for (int j = 0; j < 4; j++) GLOAD16(gA[j] + kn, (char*)(lA0 + nxt * ABUF) + offA[j]);
            #pragma unroll
            for (int j = 0; j < 2; j++) GLOAD16(gB[j] + kn, (char*)(lB0 + nxt * BBUF) + offB[j]);
        }
        const unsigned short* bufA = lA0 + cur * ABUF;
        const unsigned short* bufB = lB0 + cur * BBUF;
        #pragma unroll
        for (int step = 0; step < 2; step++) {
            int gc = step * 2 + half;
            v8s af[4], bf[2];
            #pragma unroll
            for (int mi = 0; mi < 4; mi++)
                af[mi] = *(const v8s*)&bufA[am[mi] * 32 + ((gc ^ ((am[mi] >> 1) & 3)) * 8)];
            #pragma unroll
            for (int ni = 0; ni < 2; ni++)
                bf[ni] = *(const v8s*)&bufB[bn[ni] * 32 + ((gc ^ ((bn[ni] >> 1) & 3)) * 8)];
            #pragma unroll
            for (int mi = 0; mi < 4; mi++)
                #pragma unroll
                for (int ni = 0; ni < 2; ni++)
                    acc[mi][ni] = __builtin_amdgcn_mfma_f32_32x32x16_bf16(af[mi], bf[ni], acc[mi][ni], 0, 0, 0);
        }
    }
    float scl = (n0 >= 1024) ? 0.125f : 1.0f;   // K section pre-scaled by D^-0.5
    #pragma unroll
    for (int mi = 0; mi < 4; mi++) {
        #pragma unroll
        for (int ni = 0; ni < 2; ni++) {
            int col = n0 + wn * 64 + ni * 32 + l32;
            #pragma unroll
            for (int r = 0; r < 16; r++) {
                int row = m0 + wm * 128 + mi * 32 + (r & 3) + 8 * (r >> 2) + 4 * half;
                Cout[(size_t)row * ldc + col] = f2b(acc[mi][ni][r] * scl);
            }
        }
    }
}

// ---------------- GEMM V: 128x128, 3-stage pipeline, XCD stripe; writes Vt transposed ---
__global__ __launch_bounds__(256, 3) void gemm_v(const unsigned short* __restrict__ A,
                                                 const unsigned short* __restrict__ Bt,
                                                 unsigned short* __restrict__ Vt,
                                                 int M, int N, int K) {
    constexpr int ABUF = 128 * 32;
    constexpr int BBUF = 128 * 32;
    __shared__ unsigned short lA[3 * ABUF];
    __shared__ unsigned short lB[3 * BBUF];

    int tid = threadIdx.x;
    int lane = tid & 63, w = tid >> 6;
    int half = lane >> 5, l32 = lane & 31;
    int wm = w >> 1, wn = w & 1;

    int g = blockIdx.x;
    int nbm = M / 128;
    int stripe = nbm >> 3;
    int xcd = g & 7, s = g >> 3;
    int m0 = (xcd * stripe + (s % stripe)) * 128;
    int n0 = (s / stripe) * 128;

    const unsigned short* gA[2];
    int offA[2];
    #pragma unroll
    for (int j = 0; j < 2; j++) {
        int c = j * 256 + tid;
        int row = c >> 2;
        int col8 = ((c & 3) ^ ((row >> 1) & 3)) * 8;
        gA[j] = A + (size_t)(m0 + row) * K + col8;
        offA[j] = (j * 256 + w * 64) * 16;
    }
    const unsigned short* gB[2];
    int offB[2];
    #pragma unroll
    for (int j = 0; j < 2; j++) {
        int c = j * 256 + tid;
        int row = c >> 2;
        int col8 = ((c & 3) ^ ((row >> 1) & 3)) * 8;
        gB[j] = Bt + (size_t)(n0 + row) * K + col8;
        offB[j] = (j * 256 + w * 64) * 16;
    }

    int am[2], bn[2];
    #pragma unroll
    for (int mi = 0; mi < 2; mi++) am[mi] = wm * 64 + mi * 32 + l32;
    #pragma unroll
    for (int ni = 0; ni < 2; ni++) bn[ni] = wn * 64 + ni * 32 + l32;

    v16f acc[2][2];
    #pragma unroll
    for (int mi = 0; mi < 2; mi++)
        #pragma unroll
        for (int ni = 0; ni < 2; ni++)
            #pragma unroll
            for (int r = 0; r < 16; r++) acc[mi][ni][r] = 0.f;

    int kt = K >> 5;
    #pragma unroll
    for (int j = 0; j < 2; j++) GLOAD16(gA[j], (char*)lA + offA[j]);
    #pragma unroll
    for (int j = 0; j < 2; j++) GLOAD16(gB[j], (char*)lB + offB[j]);
    #pragma unroll
    for (int j = 0; j < 2; j++) GLOAD16(gA[j] + 32, (char*)(lA + ABUF) + offA[j]);
    #pragma unroll
    for (int j = 0; j < 2; j++) GLOAD16(gB[j] + 32, (char*)(lB + BBUF) + offB[j]);

    int cur = 0;
    for (int it = 0; it < kt; it++) {
        int nx2 = cur + 2; if (nx2 >= 3) nx2 -= 3;
        __asm__ volatile("s_waitcnt vmcnt(4)" ::: "memory");
        __asm__ volatile("s_barrier" ::: "memory");
        {
            int kn = ((it + 2 < kt) ? it + 2 : kt - 1) << 5;
            #pragma unroll
            for (int j = 0; j < 2; j++) GLOAD16(gA[j] + kn, (char*)(lA + nx2 * ABUF) + offA[j]);
            #pragma unroll
            for (int j = 0; j < 2; j++) GLOAD16(gB[j] + kn, (char*)(lB + nx2 * BBUF) + offB[j]);
        }
        const unsigned short* bufA = lA + cur * ABUF;
        const unsigned short* bufB = lB + cur * BBUF;
        #pragma unroll
        for (int step = 0; step < 2; step++) {
            int gch = step * 2 + half;
            v8s af[2], bf[2];
            #pragma unroll
            for (int mi = 0; mi < 2; mi++)
                af[mi] = *(const v8s*)&bufA[am[mi] * 32 + ((gch ^ ((am[mi] >> 1) & 3)) * 8)];
            #pragma unroll
            for (int ni = 0; ni < 2; ni++)
                bf[ni] = *(const v8s*)&bufB[bn[ni] * 32 + ((gch ^ ((bn[ni] >> 1) & 3)) * 8)];
            #pragma unroll
            for (int mi = 0; mi < 2; mi++)
                #pragma unroll
                for (int ni = 0; ni < 2; ni++)
                    acc[mi][ni] = __builtin_amdgcn_mfma_f32_32x32x16_bf16(af[mi], bf[ni], acc[mi][ni], 0, 0, 0);
        }
        cur = cur + 1; if (cur >= 3) cur -= 3;
    }
    // epilogue: transpose 128(t) x 128(h*64+d) tile -> Vt[b,h,d,t]; 2 passes of 64 cols
    unsigned short* sT = lA;                 // 64 x 136 staging (reuse, 17.4 KB)
    int bB = m0 >> 10;
    int t0 = m0 & 1023;
    #pragma unroll
    for (int p = 0; p < 2; p++) {
        __syncthreads();
        if (wn == p) {
            #pragma unroll
            for (int mi = 0; mi < 2; mi++)
                #pragma unroll
                for (int ni = 0; ni < 2; ni++) {
                    int cl = ni * 32 + l32;
                    #pragma unroll
                    for (int r = 0; r < 16; r++) {
                        int rowl = wm * 64 + mi * 32 + (r & 3) + 8 * (r >> 2) + 4 * half;
                        sT[cl * 136 + rowl] = f2b(acc[mi][ni][r]);
                    }
                }
        }
        __syncthreads();
        #pragma unroll
        for (int j = 0; j < 4; j++) {
            int c = j * 256 + tid;
            int cl = c >> 4, ch = c & 15;    // 64 cols x 16 v8s-chunks of 128 rows
            int vcol = n0 + p * 64 + cl;     // = h*64 + d
            int hh = vcol >> 6, dd = vcol & 63;
            *(v8s*)&Vt[(((size_t)bB * 16 + hh) * 64 + dd) * T_ + t0 + ch * 8] =
                *(const v8s*)&sT[cl * 136 + ch * 8];
        }
    }
}

// ---------------- GEMM proj (unchanged): 128x128, 3-stage pipeline, XCD stripe ------
__global__ __launch_bounds__(256, 3) void gemm_proj(const unsigned short* __restrict__ A,
                                                    const unsigned short* __restrict__ Bt,
                                                    float* __restrict__ Cout,
                                                    const float* __restrict__ bias,
                                                    int M, int N, int K) {
    constexpr int ABUF = 128 * 32;
    constexpr int BBUF = 128 * 32;
    __shared__ unsigned short lA[3 * ABUF];
    __shared__ unsigned short lB[3 * BBUF];

    int tid = threadIdx.x;
    int lane = tid & 63, w = tid >> 6;
    int half = lane >> 5, l32 = lane & 31;
    int wm = w >> 1, wn = w & 1;

    int g = blockIdx.x;
    int nbm = M / 128;
    int stripe = nbm >> 3;
    int xcd = g & 7, s = g >> 3;
    int m0 = (xcd * stripe + (s % stripe)) * 128;
    int n0 = (s / stripe) * 128;

    const unsigned short* gA[2];
    int offA[2];
    #pragma unroll
    for (int j = 0; j < 2; j++) {
        int c = j * 256 + tid;
        int row = c >> 2;
        int col8 = ((c & 3) ^ ((row >> 1) & 3)) * 8;
        gA[j] = A + (size_t)(m0 + row) * K + col8;
        offA[j] = (j * 256 + w * 64) * 16;
    }
    const unsigned short* gB[2];
    int offB[2];
    #pragma unroll
    for (int j = 0; j < 2; j++) {
        int c = j * 256 + tid;
        int row = c >> 2;
        int col8 = ((c & 3) ^ ((row >> 1) & 3)) * 8;
        gB[j] = Bt + (size_t)(n0 + row) * K + col8;
        offB[j] = (j * 256 + w * 64) * 16;
    }

    int am[2], bn[2];
    #pragma unroll
    for (int mi = 0; mi < 2; mi++) am[mi] = wm * 64 + mi * 32 + l32;
    #pragma unroll
    for (int ni = 0; ni < 2; ni++) bn[ni] = wn * 64 + ni * 32 + l32;

    v16f acc[2][2];
    #pragma unroll
    for (int mi = 0; mi < 2; mi++)
        #pragma unroll
        for (int ni = 0; ni < 2; ni++)
            #pragma unroll
            for (int r = 0; r < 16; r++) acc[mi][ni][r] = 0.f;

    int kt = K >> 5;
    #pragma unroll
    for (int j = 0; j < 2; j++) GLOAD16(gA[j], (char*)lA + offA[j]);
    #pragma unroll
    for (int j = 0; j < 2; j++) GLOAD16(gB[j], (char*)lB + offB[j]);
    #pragma unroll
    for (int j = 0; j < 2; j++) GLOAD16(gA[j] + 32, (char*)(lA + ABUF) + offA[j]);
    #pragma unroll
    for (int j = 0; j < 2; j++) GLOAD16(gB[j] + 32, (char*)(lB + BBUF) + offB[j]);

    int cur = 0;
    for (int it = 0; it < kt; it++) {
        int nx2 = cur + 2; if (nx2 >= 3) nx2 -= 3;
        __asm__ volatile("s_waitcnt vmcnt(4)" ::: "memory");
        __asm__ volatile("s_barrier" ::: "memory");
        {
            int kn = ((it + 2 < kt) ? it + 2 : kt - 1) << 5;
            #pragma unroll
            for (int j = 0; j < 2; j++) GLOAD16(gA[j] + kn, (char*)(lA + nx2 * ABUF) + offA[j]);
            #pragma unroll
            for (int j = 0; j < 2; j++) GLOAD16(gB[j] + kn, (char*)(lB + nx2 * BBUF) + offB[j]);
        }
        const unsigned short* bufA = lA + cur * ABUF;
        const unsigned short* bufB = lB + cur * BBUF;
        #pragma unroll
        for (int step = 0; step < 2; step++) {
            int gch = step * 2 + half;
            v8s af[2], bf[2];
            #pragma unroll
            for (int mi = 0; mi < 2; mi++)
                af[mi] = *(const v8s*)&bufA[am[mi] * 32 + ((gch ^ ((am[mi] >> 1) & 3)) * 8)];
            #pragma unroll
            for (int ni = 0; ni < 2; ni++)
                bf[ni] = *(const v8s*)&bufB[bn[ni] * 32 + ((gch ^ ((bn[ni] >> 1) & 3)) * 8)];
            #pragma unroll
            for (int mi = 0; mi < 2; mi++)
                #pragma unroll
                for (int ni = 0; ni < 2; ni++)
                    acc[mi][ni] = __builtin_amdgcn_mfma_f32_32x32x16_bf16(af[mi], bf[ni], acc[mi][ni], 0, 0, 0);
        }
        cur = cur + 1; if (cur >= 3) cur -= 3;
    }
    #pragma unroll
    for (int mi = 0; mi < 2; mi++) {
        #pragma unroll
        for (int ni = 0; ni < 2; ni++) {
            int col = n0 + wn * 64 + ni * 32 + l32;
            #pragma unroll
            for (int r = 0; r < 16; r++) {
                int row = m0 + wm * 64 + mi * 32 + (r & 3) + 8 * (r >> 2) + 4 * half;
                Cout[(size_t)row * N + col] = acc[mi][ni][r] + bias[col];
            }
        }
    }
}

// ---------------- Flash attention v6: 64-row q blocks, K+V both double-buffered ---------
__global__ __launch_bounds__(256) void attn_kernel(const unsigned short* __restrict__ QKV,
                                                   const unsigned short* __restrict__ Vt,
                                                   unsigned short* __restrict__ Ob) {
    int bh = blockIdx.x;
    int qt = 15 - blockIdx.y;     // longest blocks dispatched first
    int b = bh >> 4, h = bh & 15;
    int tid = threadIdx.x, lane = tid & 63, w = tid >> 6;
    int quad = lane >> 4, l16 = lane & 15;
    int qg0 = qt * 64 + w * 16;   // each warp owns 16 q-rows

    __shared__ unsigned short lK[2][2][64][32];   // [buf][dhalf][s][32] 16 KB
    __shared__ unsigned short lV[2][2][64][32];   // [buf][shalf][d][32] 16 KB

    v8s aq0, aq1;
    {
        const unsigned short* qp = QKV + (size_t)(b * T_ + qg0 + l16) * QKVLD + h * 64;
        aq0 = *(const v8s*)(qp + quad * 8);
        aq1 = *(const v8s*)(qp + 32 + quad * 8);
    }

    const unsigned short* gK[2];
    const unsigned short* gV[2];
    int ldsOff[2];
    #pragma unroll
    for (int j = 0; j < 2; j++) {
        int c = j * 256 + tid;
        int halfp = c >> 8, row = (c >> 2) & 63;
        int col8 = ((c & 3) ^ ((row >> 1) & 3)) * 8;
        gK[j] = QKV + (size_t)(b * T_ + row) * QKVLD + 1024 + h * 64 + halfp * 32 + col8;
        gV[j] = Vt + ((size_t)bh * 64 + row) * T_ + halfp * 32 + col8;
        ldsOff[j] = (j * 256 + w * 64) * 16;
    }
    int rcol = (quad ^ ((l16 >> 1) & 3)) * 8;

    v4f accO[4];
    float lsum = 0.f;
    #pragma unroll
    for (int i = 0; i < 4; i++) accO[i] = (v4f){0.f, 0.f, 0.f, 0.f};

    int ntiles = qt + 1;

    // prologue: K[0], V[0] -> buf 0
    #pragma unroll
    for (int j = 0; j < 2; j++) GLOAD16(gK[j], (char*)&lK[0][0][0][0] + ldsOff[j]);
    #pragma unroll
    for (int j = 0; j < 2; j++) GLOAD16(gV[j], (char*)&lV[0][0][0][0] + ldsOff[j]);

    for (int it = 0; it < ntiles; it++) {
        int cur = it & 1, nxt = cur ^ 1;
        int s0 = it * 64;
        __asm__ volatile("s_waitcnt vmcnt(0)" ::: "memory");
        __asm__ volatile("s_barrier" ::: "memory");
        {
            int itn = (it + 1 < ntiles) ? it + 1 : it;
            size_t koff = (size_t)itn * 64 * QKVLD;
            #pragma unroll
            for (int j = 0; j < 2; j++)
                GLOAD16(gK[j] + koff, (char*)&lK[nxt][0][0][0] + ldsOff[j]);
            size_t voff = (size_t)itn * 64;
            #pragma unroll
            for (int j = 0; j < 2; j++)
                GLOAD16(gV[j] + voff, (char*)&lV[nxt][0][0][0] + ldsOff[j]);
        }
        // QK^T: S-transposed (row = s, col = q)
        v4f sf[4];
        #pragma unroll
        for (int nt = 0; nt < 4; nt++) {
            v8s bk0 = *(const v8s*)&lK[cur][0][nt * 16 + l16][rcol];
            v8s bk1 = *(const v8s*)&lK[cur][1][nt * 16 + l16][rcol];
            v4f a = (v4f){0.f, 0.f, 0.f, 0.f};
            a = MFMA32(bk0, aq0, a);
            a = MFMA32(bk1, aq1, a);
            sf[nt] = a;
        }
        bool diag = (it == ntiles - 1);
        int qg = qg0 + l16;
        v4s pP[4];
        #pragma unroll
        for (int nt = 0; nt < 4; nt++) {
            float p[4];
            #pragma unroll
            for (int r = 0; r < 4; r++) {
                float e = __expf(sf[nt][r]);
                if (diag) {
                    int sg = s0 + nt * 16 + quad * 4 + r;
                    e = (sg > qg) ? 0.f : e;
                }
                p[r] = e;
                lsum += e;
            }
            pP[nt] = pack4(p[0], p[1], p[2], p[3]);
        }
        // PV directly from lV[cur] (prefetched last iteration)
        #pragma unroll
        for (int kb = 0; kb < 4; kb++) {
            int sc_ = kb >> 1;
            int ccg = (kb & 1) * 2 + (quad >> 1);
            #pragma unroll
            for (int dt = 0; dt < 4; dt++) {
                int d = dt * 16 + l16;
                int ccp = ccg ^ ((l16 >> 1) & 3);
                v4s bv = *(const v4s*)&lV[cur][sc_][d][ccp * 8 + (quad & 1) * 4];
                accO[dt] = MFMA16(pP[kb], bv, accO[dt]);
            }
        }
    }
    float ls = lsum;
    ls += __shfl_xor(ls, 16, 64);
    ls += __shfl_xor(ls, 32, 64);
    #pragma unroll
    for (int r = 0; r < 4; r++) {
        float lq = __shfl(ls, quad * 4 + r, 64);
        float inv = 1.0f / lq;
        int q = qg0 + quad * 4 + r;
        #pragma unroll
        for (int dt = 0; dt < 4; dt++) {
            int d = dt * 16 + l16;
            Ob[(size_t)(b * T_ + q) * (H_ * D_) + h * 64 + d] = f2b(accO[dt][r] * inv);
        }
    }
}

extern "C" void kernel_launch(void* const* d_in, const int* in_sizes, int n_in,
                              void* d_out, int out_size, void* d_ws, size_t ws_size,
                              hipStream_t stream) {
    const float* x     = (const float*)d_in[0];
    const float* Wq    = (const float*)d_in[1];
    const float* Wk    = (const float*)d_in[2];
    const float* Wv    = (const float*)d_in[3];
    const float* Wproj = (const float*)d_in[4];
    const float* bproj = (const float*)d_in[5];
    float* out = (float*)d_out;

    char* ws = (char*)d_ws;
    unsigned short* xb     = (unsigned short*)ws;                          // 16 MB  [8192][1024]
    unsigned short* WqkvT  = (unsigned short*)(ws + 16777216);             // 6 MB   [3072][1024]
    unsigned short* WprojT = (unsigned short*)(ws + 23068672);             // 2 MB   [1024][1024]
    unsigned short* QKV    = (unsigned short*)(ws + 25165824);             // 48 MB  [8192][3072] (Q|K used)
    unsigned short* Vt     = (unsigned short*)(ws + 75497472);             // 16 MB  [B,H,D,T]
    unsigned short* Ob     = (unsigned short*)(ws + 92274688);             // 16 MB  [8192][1024]

    prep_kernel<<<dim3(9216), dim3(256), 0, stream>>>(x, Wq, Wk, Wv, Wproj, xb, WqkvT, WprojT);
    gemm_qk<<<dim3(512), dim3(256), 0, stream>>>(xb, WqkvT, QKV, 1024, QKVLD);
    gemm_v<<<dim3(512), dim3(256), 0, stream>>>(xb, WqkvT + (size_t)2048 * 1024, Vt, 8192, 1024, 1024);
    attn_kernel<<<dim3(128, 16), dim3(256), 0, stream>>>(QKV, Vt, Ob);
    gemm_proj<<<dim3(512), dim3(256), 0, stream>>>(Ob, WprojT, out, bproj, 8192, 1024, 1024);
}

// Round 13
// 230.923 us; speedup vs baseline: 1.0182x; 1.0182x over previous
//
#include <hip/hip_runtime.h>
#include <hip/hip_bf16.h>

#define B_ 8
#define T_ 1024
#define C_ 1024
#define H_ 16
#define D_ 64
#define QKVLD 3072  // [Q(1024) | K(1024) | V(unused)] ; col = part*1024 + h*64 + d

typedef short v4s __attribute__((ext_vector_type(4)));
typedef short v8s __attribute__((ext_vector_type(8)));
typedef float v4f __attribute__((ext_vector_type(4)));
typedef float v16f __attribute__((ext_vector_type(16)));

__device__ __forceinline__ unsigned short f2b(float f) {
    unsigned int u = __builtin_bit_cast(unsigned int, f);
    unsigned int lsb = (u >> 16) & 1u;
    u += 0x7fffu + lsb;
    return (unsigned short)(u >> 16);
}

__device__ __forceinline__ v4s pack4(float p0, float p1, float p2, float p3) {
    unsigned int a = (__builtin_bit_cast(unsigned int, p0) + 0x8000u) >> 16;
    unsigned int b = (__builtin_bit_cast(unsigned int, p1) + 0x8000u) & 0xFFFF0000u;
    unsigned int c = (__builtin_bit_cast(unsigned int, p2) + 0x8000u) >> 16;
    unsigned int d = (__builtin_bit_cast(unsigned int, p3) + 0x8000u) & 0xFFFF0000u;
    union { unsigned int u[2]; v4s v; } t;
    t.u[0] = a | b; t.u[1] = c | d;
    return t.v;
}

#define MFMA32(A, B, C) __builtin_amdgcn_mfma_f32_16x16x32_bf16(A, B, C, 0, 0, 0)
#define MFMA16(A, B, C) __builtin_amdgcn_mfma_f32_16x16x16bf16_1k(A, B, C, 0, 0, 0)

#define GLOAD16(gp, lp)                                                          \
    __builtin_amdgcn_global_load_lds(                                            \
        (const __attribute__((address_space(1))) unsigned int*)(gp),             \
        (__attribute__((address_space(3))) unsigned int*)(lp), 16, 0, 0)

// ---------------- fused prep: cast x + transpose Wqkv + transpose Wproj ----------------
__global__ void prep_kernel(const float* __restrict__ x, const float* __restrict__ Wq,
                            const float* __restrict__ Wk, const float* __restrict__ Wv,
                            const float* __restrict__ Wproj,
                            unsigned short* __restrict__ xb,
                            unsigned short* __restrict__ WqkvT,
                            unsigned short* __restrict__ WprojT) {
    __shared__ unsigned short t[64][65];
    int g = blockIdx.x;
    if (g < 8192) {
        int i = (g * 256 + (int)threadIdx.x) * 4;
        float4 v = *(const float4*)(x + i);
        ushort4 o;
        o.x = f2b(v.x); o.y = f2b(v.y); o.z = f2b(v.z); o.w = f2b(v.w);
        *(ushort4*)(xb + i) = o;
    } else if (g < 8192 + 768) {
        int idx = g - 8192;
        int z = idx >> 4;
        int h = z / 3, part = z % 3;
        const float* src = (part == 0 ? Wq : (part == 1 ? Wk : Wv)) + (size_t)h * C_ * D_;
        int c0 = (idx & 15) * 64;
        for (int i = threadIdx.x; i < 4096; i += 256) {
            int r = i >> 6, d = i & 63;
            t[d][r] = f2b(src[(size_t)(c0 + r) * D_ + d]);
        }
        __syncthreads();
        unsigned short* dst = WqkvT + (size_t)(part * 1024 + h * 64) * C_;
        for (int i = threadIdx.x; i < 4096; i += 256) {
            int d = i >> 6, r = i & 63;
            dst[(size_t)d * C_ + c0 + r] = t[d][r];
        }
    } else {
        int idx = g - 8960;
        int n0 = (idx & 15) * 64, k0 = (idx >> 4) * 64;
        for (int i = threadIdx.x; i < 4096; i += 256) {
            int r = i >> 6, c = i & 63;
            t[c][r] = f2b(Wproj[(size_t)(k0 + r) * C_ + n0 + c]);
        }
        __syncthreads();
        for (int i = threadIdx.x; i < 4096; i += 256) {
            int n = i >> 6, k = i & 63;
            WprojT[(size_t)(n0 + n) * 1024 + k0 + k] = t[n][k];
        }
    }
}

// ---------------- Fused QK+V GEMM: 1024 blocks, BANK-INTERLEAVED heavy/light mix --------
// bank = g>>3 (8 consecutive blocks share dispatch wave across XCDs, xcd = g&7).
// Even bank -> QK block (256x128, R2-exact 2-stage drain, XCD-stripe: 512 blocks).
// Odd  bank -> V block (128x128, 3-stage counted pipeline, XCD-stripe: 512 blocks).
// Each CU gets one heavy + one light resident -> V loads fill QK's drain stalls (R8's
// serial heavy-then-light rounds cost 75 us; interleave targets ~64-68).
// j = g>>4 indexes within each type; both maps bijective. K section pre-scaled 0.125.
__global__ __launch_bounds__(256, 2) void gemm_qkv(const unsigned short* __restrict__ A,
                                                   const unsigned short* __restrict__ Bt,
                                                   unsigned short* __restrict__ Cout,
                                                   unsigned short* __restrict__ Vt,
                                                   int K, int ldc) {
    __shared__ unsigned short smem[24576];   // 48 KB, carved per branch

    int tid = threadIdx.x;
    int lane = tid & 63, w = tid >> 6;
    int half = lane >> 5, l32 = lane & 31;
    int wm = w >> 1, wn = w & 1;
    int g = blockIdx.x;
    int xcd = g & 7;
    int bank = g >> 3;
    int j = g >> 4;          // per-type index component, [0,64)

    if ((bank & 1) == 0) {
        // ---------------- QK branch: R2-exact 256x128, 2-stage drain, XCD stripe -----
        constexpr int ABUF = 256 * 32;
        constexpr int BBUF = 128 * 32;
        unsigned short* lA0 = smem;              // 2*ABUF = 16384 shorts
        unsigned short* lB0 = smem + 2 * ABUF;   // 2*BBUF = 8192 shorts

        int m0 = (xcd * 4 + (j & 3)) * 256;
        int n0 = (j >> 2) * 128;

        const unsigned short* gA[4];
        int offA[4];
        #pragma unroll
        for (int jj = 0; jj < 4; jj++) {
            int c = jj * 256 + tid;
            int row = c >> 2;
            int col8 = ((c & 3) ^ ((row >> 1) & 3)) * 8;
            gA[jj] = A + (size_t)(m0 + row) * K + col8;
            offA[jj] = (jj * 256 + w * 64) * 16;
        }
        const unsigned short* gB[2];
        int offB[2];
        #pragma unroll
        for (int jj = 0; jj < 2; jj++) {
            int c = jj * 256 + tid;
            int row = c >> 2;
            int col8 = ((c & 3) ^ ((row >> 1) & 3)) * 8;
            gB[jj] = Bt + (size_t)(n0 + row) * K + col8;
            offB[jj] = (jj * 256 + w * 64) * 16;
        }

        int am[4], bn[2];
        #pragma unroll
        for (int mi = 0; mi < 4; mi++) am[mi] = wm * 128 + mi * 32 + l32;
        #pragma unroll
        for (int ni = 0; ni < 2; ni++) bn[ni] = wn * 64 + ni * 32 + l32;

        v16f acc[4][2];
        #pragma unroll
        for (int mi = 0; mi < 4; mi++)
            #pragma unroll
            for (int ni = 0; ni < 2; ni++)
                #pragma unroll
                for (int r = 0; r < 16; r++) acc[mi][ni][r] = 0.f;

        int ktiles = K >> 5;
        #pragma unroll
        for (int jj = 0; jj < 4; jj++) GLOAD16(gA[jj], (char*)lA0 + offA[jj]);
        #pragma unroll
        for (int jj = 0; jj < 2; jj++) GLOAD16(gB[jj], (char*)lB0 + offB[jj]);

        for (int it = 0; it < ktiles; it++) {
            int cur = it & 1, nxt = cur ^ 1;
            __asm__ volatile("s_waitcnt vmcnt(0)" ::: "memory");
            __asm__ volatile("s_barrier" ::: "memory");
            {
                int kn = (it + 1 < ktiles) ? (it + 1) * 32 : it * 32;
                #pragma unroll
                for (int jj = 0; jj < 4; jj++) GLOAD16(gA[jj] + kn, (char*)(lA0 + nxt * ABUF) + offA[jj]);
                #pragma unroll
                for (int jj = 0; jj < 2; jj++) GLOAD16(gB[jj] + kn, (char*)(lB0 + nxt * BBUF) + offB[jj]);
            }
            const unsigned short* bufA = lA0 + cur * ABUF;
            const unsigned short* bufB = lB0 + cur * BBUF;
            #pragma unroll
            for (int step = 0; step < 2; step++) {
                int gc = step * 2 + half;
                v8s af[4], bf[2];
                #pragma unroll
                for (int mi = 0; mi < 4; mi++)
                    af[mi] = *(const v8s*)&bufA[am[mi] * 32 + ((gc ^ ((am[mi] >> 1) & 3)) * 8)];
                #pragma unroll
                for (int ni = 0; ni < 2; ni++)
                    bf[ni] = *(const v8s*)&bufB[bn[ni] * 32 + ((gc ^ ((bn[ni] >> 1) & 3)) * 8)];
                #pragma unroll
                for (int mi = 0; mi < 4; mi++)
                    #pragma unroll
                    for (int ni = 0; ni < 2; ni++)
                        acc[mi][ni] = __builtin_amdgcn_mfma_f32_32x32x16_bf16(af[mi], bf[ni], acc[mi][ni], 0, 0, 0);
            }
        }
        float scl = (n0 >= 1024) ? 0.125f : 1.0f;   // K section pre-scaled by D^-0.5
        #pragma unroll
        for (int mi = 0; mi < 4; mi++) {
            #pragma unroll
            for (int ni = 0; ni < 2; ni++) {
                int col = n0 + wn * 64 + ni * 32 + l32;
                #pragma unroll
                for (int r = 0; r < 16; r++) {
                    int row = m0 + wm * 128 + mi * 32 + (r & 3) + 8 * (r >> 2) + 4 * half;
                    Cout[(size_t)row * ldc + col] = f2b(acc[mi][ni][r] * scl);
                }
            }
        }
    } else {
        // ---------------- V branch: R2-exact 128x128, 3-stage, XCD stripe ------------
        constexpr int ABUF = 128 * 32;
        constexpr int BBUF = 128 * 32;
        unsigned short* lA = smem;               // 3*ABUF = 12288 shorts
        unsigned short* lB = smem + 3 * ABUF;    // 3*BBUF = 12288 shorts

        const unsigned short* Bv = Bt + (size_t)2048 * K;   // V rows of WqkvT
        int m0 = (xcd * 8 + (j & 7)) * 128;
        int n0 = (j >> 3) * 128;

        const unsigned short* gA[2];
        int offA[2];
        #pragma unroll
        for (int jj = 0; jj < 2; jj++) {
            int c = jj * 256 + tid;
            int row = c >> 2;
            int col8 = ((c & 3) ^ ((row >> 1) & 3)) * 8;
            gA[jj] = A + (size_t)(m0 + row) * K + col8;
            offA[jj] = (jj * 256 + w * 64) * 16;
        }
        const unsigned short* gB[2];
        int offB[2];
        #pragma unroll
        for (int jj = 0; jj < 2; jj++) {
            int c = jj * 256 + tid;
            int row = c >> 2;
            int col8 = ((c & 3) ^ ((row >> 1) & 3)) * 8;
            gB[jj] = Bv + (size_t)(n0 + row) * K + col8;
            offB[jj] = (jj * 256 + w * 64) * 16;
        }

        int am[2], bn[2];
        #pragma unroll
        for (int mi = 0; mi < 2; mi++) am[mi] = wm * 64 + mi * 32 + l32;
        #pragma unroll
        for (int ni = 0; ni < 2; ni++) bn[ni] = wn * 64 + ni * 32 + l32;

        v16f acc[2][2];
        #pragma unroll
        for (int mi = 0; mi < 2; mi++)
            #pragma unroll
            for (int ni = 0; ni < 2; ni++)
                #pragma unroll
                for (int r = 0; r < 16; r++) acc[mi][ni][r] = 0.f;

        int kt = K >> 5;
        #pragma unroll
        for (int jj = 0; jj < 2; jj++) GLOAD16(gA[jj], (char*)lA + offA[jj]);
        #pragma unroll
        for (int jj = 0; jj < 2; jj++) GLOAD16(gB[jj], (char*)lB + offB[jj]);
        #pragma unroll
        for (int jj = 0; jj < 2; jj++) GLOAD16(gA[jj] + 32, (char*)(lA + ABUF) + offA[jj]);
        #pragma unroll
        for (int jj = 0; jj < 2; jj++) GLOAD16(gB[jj] + 32, (char*)(lB + BBUF) + offB[jj]);

        int cur = 0;
        for (int it = 0; it < kt; it++) {
            int nx2 = cur + 2; if (nx2 >= 3) nx2 -= 3;
            __asm__ volatile("s_waitcnt vmcnt(4)" ::: "memory");
            __asm__ volatile("s_barrier" ::: "memory");
            {
                int kn = ((it + 2 < kt) ? it + 2 : kt - 1) << 5;
                #pragma unroll
                for (int jj = 0; jj < 2; jj++) GLOAD16(gA[jj] + kn, (char*)(lA + nx2 * ABUF) + offA[jj]);
                #pragma unroll
                for (int jj = 0; jj < 2; jj++) GLOAD16(gB[jj] + kn, (char*)(lB + nx2 * BBUF) + offB[jj]);
            }
            const unsigned short* bufA = lA + cur * ABUF;
            const unsigned short* bufB = lB + cur * BBUF;
            #pragma unroll
            for (int step = 0; step < 2; step++) {
                int gch = step * 2 + half;
                v8s af[2], bf[2];
                #pragma unroll
                for (int mi = 0; mi < 2; mi++)
                    af[mi] = *(const v8s*)&bufA[am[mi] * 32 + ((gch ^ ((am[mi] >> 1) & 3)) * 8)];
                #pragma unroll
                for (int ni = 0; ni < 2; ni++)
                    bf[ni] = *(const v8s*)&bufB[bn[ni] * 32 + ((gch ^ ((bn[ni] >> 1) & 3)) * 8)];
                #pragma unroll
                for (int mi = 0; mi < 2; mi++)
                    #pragma unroll
                    for (int ni = 0; ni < 2; ni++)
                        acc[mi][ni] = __builtin_amdgcn_mfma_f32_32x32x16_bf16(af[mi], bf[ni], acc[mi][ni], 0, 0, 0);
            }
            cur = cur + 1; if (cur >= 3) cur -= 3;
        }
        // epilogue: transpose 128(t) x 128(h*64+d) tile -> Vt[b,h,d,t]; 2 passes of 64 cols
        unsigned short* sT = lA;                 // 64 x 136 staging (reuse, 17.4 KB)
        int bB = m0 >> 10;
        int t0 = m0 & 1023;
        #pragma unroll
        for (int p = 0; p < 2; p++) {
            __syncthreads();
            if (wn == p) {
                #pragma unroll
                for (int mi = 0; mi < 2; mi++)
                    #pragma unroll
                    for (int ni = 0; ni < 2; ni++) {
                        int cl = ni * 32 + l32;
                        #pragma unroll
                        for (int r = 0; r < 16; r++) {
                            int rowl = wm * 64 + mi * 32 + (r & 3) + 8 * (r >> 2) + 4 * half;
                            sT[cl * 136 + rowl] = f2b(acc[mi][ni][r]);
                        }
                    }
            }
            __syncthreads();
            #pragma unroll
            for (int jj = 0; jj < 4; jj++) {
                int c = jj * 256 + tid;
                int cl = c >> 4, ch = c & 15;    // 64 cols x 16 v8s-chunks of 128 rows
                int vcol = n0 + p * 64 + cl;     // = h*64 + d
                int hh = vcol >> 6, dd = vcol & 63;
                *(v8s*)&Vt[(((size_t)bB * 16 + hh) * 64 + dd) * T_ + t0 + ch * 8] =
                    *(const v8s*)&sT[cl * 136 + ch * 8];
            }
        }
    }
}

// ---------------- GEMM proj (unchanged): 128x128, 3-stage pipeline, XCD stripe ------
__global__ __launch_bounds__(256, 3) void gemm_proj(const unsigned short* __restrict__ A,
                                                    const unsigned short* __restrict__ Bt,
                                                    float* __restrict__ Cout,
                                                    const float* __restrict__ bias,
                                                    int M, int N, int K) {
    constexpr int ABUF = 128 * 32;
    constexpr int BBUF = 128 * 32;
    __shared__ unsigned short lA[3 * ABUF];
    __shared__ unsigned short lB[3 * BBUF];

    int tid = threadIdx.x;
    int lane = tid & 63, w = tid >> 6;
    int half = lane >> 5, l32 = lane & 31;
    int wm = w >> 1, wn = w & 1;

    int g = blockIdx.x;
    int nbm = M / 128;
    int stripe = nbm >> 3;
    int xcd = g & 7, s = g >> 3;
    int m0 = (xcd * stripe + (s % stripe)) * 128;
    int n0 = (s / stripe) * 128;

    const unsigned short* gA[2];
    int offA[2];
    #pragma unroll
    for (int j = 0; j < 2; j++) {
        int c = j * 256 + tid;
        int row = c >> 2;
        int col8 = ((c & 3) ^ ((row >> 1) & 3)) * 8;
        gA[j] = A + (size_t)(m0 + row) * K + col8;
        offA[j] = (j * 256 + w * 64) * 16;
    }
    const unsigned short* gB[2];
    int offB[2];
    #pragma unroll
    for (int j = 0; j < 2; j++) {
        int c = j * 256 + tid;
        int row = c >> 2;
        int col8 = ((c & 3) ^ ((row >> 1) & 3)) * 8;
        gB[j] = Bt + (size_t)(n0 + row) * K + col8;
        offB[j] = (j * 256 + w * 64) * 16;
    }

    int am[2], bn[2];
    #pragma unroll
    for (int mi = 0; mi < 2; mi++) am[mi] = wm * 64 + mi * 32 + l32;
    #pragma unroll
    for (int ni = 0; ni < 2; ni++) bn[ni] = wn * 64 + ni * 32 + l32;

    v16f acc[2][2];
    #pragma unroll
    for (int mi = 0; mi < 2; mi++)
        #pragma unroll
        for (int ni = 0; ni < 2; ni++)
            #pragma unroll
            for (int r = 0; r < 16; r++) acc[mi][ni][r] = 0.f;

    int kt = K >> 5;
    #pragma unroll
    for (int j = 0; j < 2; j++) GLOAD16(gA[j], (char*)lA + offA[j]);
    #pragma unroll
    for (int j = 0; j < 2; j++) GLOAD16(gB[j], (char*)lB + offB[j]);
    #pragma unroll
    for (int j = 0; j < 2; j++) GLOAD16(gA[j] + 32, (char*)(lA + ABUF) + offA[j]);
    #pragma unroll
    for (int j = 0; j < 2; j++) GLOAD16(gB[j] + 32, (char*)(lB + BBUF) + offB[j]);

    int cur = 0;
    for (int it = 0; it < kt; it++) {
        int nx2 = cur + 2; if (nx2 >= 3) nx2 -= 3;
        __asm__ volatile("s_waitcnt vmcnt(4)" ::: "memory");
        __asm__ volatile("s_barrier" ::: "memory");
        {
            int kn = ((it + 2 < kt) ? it + 2 : kt - 1) << 5;
            #pragma unroll
            for (int j = 0; j < 2; j++) GLOAD16(gA[j] + kn, (char*)(lA + nx2 * ABUF) + offA[j]);
            #pragma unroll
            for (int j = 0; j < 2; j++) GLOAD16(gB[j] + kn, (char*)(lB + nx2 * BBUF) + offB[j]);
        }
        const unsigned short* bufA = lA + cur * ABUF;
        const unsigned short* bufB = lB + cur * BBUF;
        #pragma unroll
        for (int step = 0; step < 2; step++) {
            int gch = step * 2 + half;
            v8s af[2], bf[2];
            #pragma unroll
            for (int mi = 0; mi < 2; mi++)
                af[mi] = *(const v8s*)&bufA[am[mi] * 32 + ((gch ^ ((am[mi] >> 1) & 3)) * 8)];
            #pragma unroll
            for (int ni = 0; ni < 2; ni++)
                bf[ni] = *(const v8s*)&bufB[bn[ni] * 32 + ((gch ^ ((bn[ni] >> 1) & 3)) * 8)];
            #pragma unroll
            for (int mi = 0; mi < 2; mi++)
                #pragma unroll
                for (int ni = 0; ni < 2; ni++)
                    acc[mi][ni] = __builtin_amdgcn_mfma_f32_32x32x16_bf16(af[mi], bf[ni], acc[mi][ni], 0, 0, 0);
        }
        cur = cur + 1; if (cur >= 3) cur -= 3;
    }
    #pragma unroll
    for (int mi = 0; mi < 2; mi++) {
        #pragma unroll
        for (int ni = 0; ni < 2; ni++) {
            int col = n0 + wn * 64 + ni * 32 + l32;
            #pragma unroll
            for (int r = 0; r < 16; r++) {
                int row = m0 + wm * 64 + mi * 32 + (r & 3) + 8 * (r >> 2) + 4 * half;
                Cout[(size_t)row * N + col] = acc[mi][ni][r] + bias[col];
            }
        }
    }
}

// ---------------- Flash attention v6: 64-row q blocks, K+V both double-buffered ---------
__global__ __launch_bounds__(256) void attn_kernel(const unsigned short* __restrict__ QKV,
                                                   const unsigned short* __restrict__ Vt,
                                                   unsigned short* __restrict__ Ob) {
    int bh = blockIdx.x;
    int qt = 15 - blockIdx.y;     // longest blocks dispatched first
    int b = bh >> 4, h = bh & 15;
    int tid = threadIdx.x, lane = tid & 63, w = tid >> 6;
    int quad = lane >> 4, l16 = lane & 15;
    int qg0 = qt * 64 + w * 16;   // each warp owns 16 q-rows

    __shared__ unsigned short lK[2][2][64][32];   // [buf][dhalf][s][32] 16 KB
    __shared__ unsigned short lV[2][2][64][32];   // [buf][shalf][d][32] 16 KB

    v8s aq0, aq1;
    {
        const unsigned short* qp = QKV + (size_t)(b * T_ + qg0 + l16) * QKVLD + h * 64;
        aq0 = *(const v8s*)(qp + quad * 8);
        aq1 = *(const v8s*)(qp + 32 + quad * 8);
    }

    const unsigned short* gK[2];
    const unsigned short* gV[2];
    int ldsOff[2];
    #pragma unroll
    for (int j = 0; j < 2; j++) {
        int c = j * 256 + tid;
        int halfp = c >> 8, row = (c >> 2) & 63;
        int col8 = ((c & 3) ^ ((row >> 1) & 3)) * 8;
        gK[j] = QKV + (size_t)(b * T_ + row) * QKVLD + 1024 + h * 64 + halfp * 32 + col8;
        gV[j] = Vt + ((size_t)bh * 64 + row) * T_ + halfp * 32 + col8;
        ldsOff[j] = (j * 256 + w * 64) * 16;
    }
    int rcol = (quad ^ ((l16 >> 1) & 3)) * 8;

    v4f accO[4];
    float lsum = 0.f;
    #pragma unroll
    for (int i = 0; i < 4; i++) accO[i] = (v4f){0.f, 0.f, 0.f, 0.f};

    int ntiles = qt + 1;

    // prologue: K[0], V[0] -> buf 0
    #pragma unroll
    for (int j = 0; j < 2; j++) GLOAD16(gK[j], (char*)&lK[0][0][0][0] + ldsOff[j]);
    #pragma unroll
    for (int j = 0; j < 2; j++) GLOAD16(gV[j], (char*)&lV[0][0][0][0] + ldsOff[j]);

    for (int it = 0; it < ntiles; it++) {
        int cur = it & 1, nxt = cur ^ 1;
        int s0 = it * 64;
        __asm__ volatile("s_waitcnt vmcnt(0)" ::: "memory");
        __asm__ volatile("s_barrier" ::: "memory");
        {
            int itn = (it + 1 < ntiles) ? it + 1 : it;
            size_t koff = (size_t)itn * 64 * QKVLD;
            #pragma unroll
            for (int j = 0; j < 2; j++)
                GLOAD16(gK[j] + koff, (char*)&lK[nxt][0][0][0] + ldsOff[j]);
            size_t voff = (size_t)itn * 64;
            #pragma unroll
            for (int j = 0; j < 2; j++)
                GLOAD16(gV[j] + voff, (char*)&lV[nxt][0][0][0] + ldsOff[j]);
        }
        // QK^T: S-transposed (row = s, col = q)
        v4f sf[4];
        #pragma unroll
        for (int nt = 0; nt < 4; nt++) {
            v8s bk0 = *(const v8s*)&lK[cur][0][nt * 16 + l16][rcol];
            v8s bk1 = *(const v8s*)&lK[cur][1][nt * 16 + l16][rcol];
            v4f a = (v4f){0.f, 0.f, 0.f, 0.f};
            a = MFMA32(bk0, aq0, a);
            a = MFMA32(bk1, aq1, a);
            sf[nt] = a;
        }
        bool diag = (it == ntiles - 1);
        int qg = qg0 + l16;
        v4s pP[4];
        #pragma unroll
        for (int nt = 0; nt < 4; nt++) {
            float p[4];
            #pragma unroll
            for (int r = 0; r < 4; r++) {
                float e = __expf(sf[nt][r]);
                if (diag) {
                    int sg = s0 + nt * 16 + quad * 4 + r;
                    e = (sg > qg) ? 0.f : e;
                }
                p[r] = e;
                lsum += e;
            }
            pP[nt] = pack4(p[0], p[1], p[2], p[3]);
        }
        // PV directly from lV[cur] (prefetched last iteration)
        #pragma unroll
        for (int kb = 0; kb < 4; kb++) {
            int sc_ = kb >> 1;
            int ccg = (kb & 1) * 2 + (quad >> 1);
            #pragma unroll
            for (int dt = 0; dt < 4; dt++) {
                int d = dt * 16 + l16;
                int ccp = ccg ^ ((l16 >> 1) & 3);
                v4s bv = *(const v4s*)&lV[cur][sc_][d][ccp * 8 + (quad & 1) * 4];
                accO[dt] = MFMA16(pP[kb], bv, accO[dt]);
            }
        }
    }
    float ls = lsum;
    ls += __shfl_xor(ls, 16, 64);
    ls += __shfl_xor(ls, 32, 64);
    #pragma unroll
    for (int r = 0; r < 4; r++) {
        float lq = __shfl(ls, quad * 4 + r, 64);
        float inv = 1.0f / lq;
        int q = qg0 + quad * 4 + r;
        #pragma unroll
        for (int dt = 0; dt < 4; dt++) {
            int d = dt * 16 + l16;
            Ob[(size_t)(b * T_ + q) * (H_ * D_) + h * 64 + d] = f2b(accO[dt][r] * inv);
        }
    }
}

extern "C" void kernel_launch(void* const* d_in, const int* in_sizes, int n_in,
                              void* d_out, int out_size, void* d_ws, size_t ws_size,
                              hipStream_t stream) {
    const float* x     = (const float*)d_in[0];
    const float* Wq    = (const float*)d_in[1];
    const float* Wk    = (const float*)d_in[2];
    const float* Wv    = (const float*)d_in[3];
    const float* Wproj = (const float*)d_in[4];
    const float* bproj = (const float*)d_in[5];
    float* out = (float*)d_out;

    char* ws = (char*)d_ws;
    unsigned short* xb     = (unsigned short*)ws;                          // 16 MB  [8192][1024]
    unsigned short* WqkvT  = (unsigned short*)(ws + 16777216);             // 6 MB   [3072][1024]
    unsigned short* WprojT = (unsigned short*)(ws + 23068672);             // 2 MB   [1024][1024]
    unsigned short* QKV    = (unsigned short*)(ws + 25165824);             // 48 MB  [8192][3072] (Q|K used)
    unsigned short* Vt     = (unsigned short*)(ws + 75497472);             // 16 MB  [B,H,D,T]
    unsigned short* Ob     = (unsigned short*)(ws + 92274688);             // 16 MB  [8192][1024]

    prep_kernel<<<dim3(9216), dim3(256), 0, stream>>>(x, Wq, Wk, Wv, Wproj, xb, WqkvT, WprojT);
    gemm_qkv<<<dim3(1024), dim3(256), 0, stream>>>(xb, WqkvT, QKV, Vt, 1024, QKVLD);
    attn_kernel<<<dim3(128, 16), dim3(256), 0, stream>>>(QKV, Vt, Ob);
    gemm_proj<<<dim3(512), dim3(256), 0, stream>>>(Ob, WprojT, out, bproj, 8192, 1024, 1024);
}

// Round 14
// 230.332 us; speedup vs baseline: 1.0208x; 1.0026x over previous
//
#include <hip/hip_runtime.h>
#include <hip/hip_bf16.h>

#define B_ 8
#define T_ 1024
#define C_ 1024
#define H_ 16
#define D_ 64
#define QKVLD 3072  // [Q(1024) | K(1024) | V(unused)] ; col = part*1024 + h*64 + d

typedef short v4s __attribute__((ext_vector_type(4)));
typedef short v8s __attribute__((ext_vector_type(8)));
typedef float v4f __attribute__((ext_vector_type(4)));
typedef float v16f __attribute__((ext_vector_type(16)));

__device__ __forceinline__ unsigned short f2b(float f) {
    unsigned int u = __builtin_bit_cast(unsigned int, f);
    unsigned int lsb = (u >> 16) & 1u;
    u += 0x7fffu + lsb;
    return (unsigned short)(u >> 16);
}

__device__ __forceinline__ v4s pack4(float p0, float p1, float p2, float p3) {
    unsigned int a = (__builtin_bit_cast(unsigned int, p0) + 0x8000u) >> 16;
    unsigned int b = (__builtin_bit_cast(unsigned int, p1) + 0x8000u) & 0xFFFF0000u;
    unsigned int c = (__builtin_bit_cast(unsigned int, p2) + 0x8000u) >> 16;
    unsigned int d = (__builtin_bit_cast(unsigned int, p3) + 0x8000u) & 0xFFFF0000u;
    union { unsigned int u[2]; v4s v; } t;
    t.u[0] = a | b; t.u[1] = c | d;
    return t.v;
}

#define MFMA32(A, B, C) __builtin_amdgcn_mfma_f32_16x16x32_bf16(A, B, C, 0, 0, 0)
#define MFMA16(A, B, C) __builtin_amdgcn_mfma_f32_16x16x16bf16_1k(A, B, C, 0, 0, 0)

#define GLOAD16(gp, lp)                                                          \
    __builtin_amdgcn_global_load_lds(                                            \
        (const __attribute__((address_space(1))) unsigned int*)(gp),             \
        (__attribute__((address_space(3))) unsigned int*)(lp), 16, 0, 0)

// ---------------- fused prep: cast x + transpose Wqkv + transpose Wproj ----------------
__global__ void prep_kernel(const float* __restrict__ x, const float* __restrict__ Wq,
                            const float* __restrict__ Wk, const float* __restrict__ Wv,
                            const float* __restrict__ Wproj,
                            unsigned short* __restrict__ xb,
                            unsigned short* __restrict__ WqkvT,
                            unsigned short* __restrict__ WprojT) {
    __shared__ unsigned short t[64][65];
    int g = blockIdx.x;
    if (g < 8192) {
        int i = (g * 256 + (int)threadIdx.x) * 4;
        float4 v = *(const float4*)(x + i);
        ushort4 o;
        o.x = f2b(v.x); o.y = f2b(v.y); o.z = f2b(v.z); o.w = f2b(v.w);
        *(ushort4*)(xb + i) = o;
    } else if (g < 8192 + 768) {
        int idx = g - 8192;
        int z = idx >> 4;
        int h = z / 3, part = z % 3;
        const float* src = (part == 0 ? Wq : (part == 1 ? Wk : Wv)) + (size_t)h * C_ * D_;
        int c0 = (idx & 15) * 64;
        for (int i = threadIdx.x; i < 4096; i += 256) {
            int r = i >> 6, d = i & 63;
            t[d][r] = f2b(src[(size_t)(c0 + r) * D_ + d]);
        }
        __syncthreads();
        unsigned short* dst = WqkvT + (size_t)(part * 1024 + h * 64) * C_;
        for (int i = threadIdx.x; i < 4096; i += 256) {
            int d = i >> 6, r = i & 63;
            dst[(size_t)d * C_ + c0 + r] = t[d][r];
        }
    } else {
        int idx = g - 8960;
        int n0 = (idx & 15) * 64, k0 = (idx >> 4) * 64;
        for (int i = threadIdx.x; i < 4096; i += 256) {
            int r = i >> 6, c = i & 63;
            t[c][r] = f2b(Wproj[(size_t)(k0 + r) * C_ + n0 + c]);
        }
        __syncthreads();
        for (int i = threadIdx.x; i < 4096; i += 256) {
            int n = i >> 6, k = i & 63;
            WprojT[(size_t)(n0 + n) * 1024 + k0 + k] = t[n][k];
        }
    }
}

// ---------------- Fused QK+V GEMM: 1024 blocks, BANK-INTERLEAVED heavy/light mix --------
// (R13-measured best-total config; unchanged this round.)
__global__ __launch_bounds__(256, 2) void gemm_qkv(const unsigned short* __restrict__ A,
                                                   const unsigned short* __restrict__ Bt,
                                                   unsigned short* __restrict__ Cout,
                                                   unsigned short* __restrict__ Vt,
                                                   int K, int ldc) {
    __shared__ unsigned short smem[24576];   // 48 KB, carved per branch

    int tid = threadIdx.x;
    int lane = tid & 63, w = tid >> 6;
    int half = lane >> 5, l32 = lane & 31;
    int wm = w >> 1, wn = w & 1;
    int g = blockIdx.x;
    int xcd = g & 7;
    int bank = g >> 3;
    int j = g >> 4;          // per-type index component, [0,64)

    if ((bank & 1) == 0) {
        // ---------------- QK branch: R2-exact 256x128, 2-stage drain, XCD stripe -----
        constexpr int ABUF = 256 * 32;
        constexpr int BBUF = 128 * 32;
        unsigned short* lA0 = smem;              // 2*ABUF = 16384 shorts
        unsigned short* lB0 = smem + 2 * ABUF;   // 2*BBUF = 8192 shorts

        int m0 = (xcd * 4 + (j & 3)) * 256;
        int n0 = (j >> 2) * 128;

        const unsigned short* gA[4];
        int offA[4];
        #pragma unroll
        for (int jj = 0; jj < 4; jj++) {
            int c = jj * 256 + tid;
            int row = c >> 2;
            int col8 = ((c & 3) ^ ((row >> 1) & 3)) * 8;
            gA[jj] = A + (size_t)(m0 + row) * K + col8;
            offA[jj] = (jj * 256 + w * 64) * 16;
        }
        const unsigned short* gB[2];
        int offB[2];
        #pragma unroll
        for (int jj = 0; jj < 2; jj++) {
            int c = jj * 256 + tid;
            int row = c >> 2;
            int col8 = ((c & 3) ^ ((row >> 1) & 3)) * 8;
            gB[jj] = Bt + (size_t)(n0 + row) * K + col8;
            offB[jj] = (jj * 256 + w * 64) * 16;
        }

        int am[4], bn[2];
        #pragma unroll
        for (int mi = 0; mi < 4; mi++) am[mi] = wm * 128 + mi * 32 + l32;
        #pragma unroll
        for (int ni = 0; ni < 2; ni++) bn[ni] = wn * 64 + ni * 32 + l32;

        v16f acc[4][2];
        #pragma unroll
        for (int mi = 0; mi < 4; mi++)
            #pragma unroll
            for (int ni = 0; ni < 2; ni++)
                #pragma unroll
                for (int r = 0; r < 16; r++) acc[mi][ni][r] = 0.f;

        int ktiles = K >> 5;
        #pragma unroll
        for (int jj = 0; jj < 4; jj++) GLOAD16(gA[jj], (char*)lA0 + offA[jj]);
        #pragma unroll
        for (int jj = 0; jj < 2; jj++) GLOAD16(gB[jj], (char*)lB0 + offB[jj]);

        for (int it = 0; it < ktiles; it++) {
            int cur = it & 1, nxt = cur ^ 1;
            __asm__ volatile("s_waitcnt vmcnt(0)" ::: "memory");
            __asm__ volatile("s_barrier" ::: "memory");
            {
                int kn = (it + 1 < ktiles) ? (it + 1) * 32 : it * 32;
                #pragma unroll
                for (int jj = 0; jj < 4; jj++) GLOAD16(gA[jj] + kn, (char*)(lA0 + nxt * ABUF) + offA[jj]);
                #pragma unroll
                for (int jj = 0; jj < 2; jj++) GLOAD16(gB[jj] + kn, (char*)(lB0 + nxt * BBUF) + offB[jj]);
            }
            const unsigned short* bufA = lA0 + cur * ABUF;
            const unsigned short* bufB = lB0 + cur * BBUF;
            #pragma unroll
            for (int step = 0; step < 2; step++) {
                int gc = step * 2 + half;
                v8s af[4], bf[2];
                #pragma unroll
                for (int mi = 0; mi < 4; mi++)
                    af[mi] = *(const v8s*)&bufA[am[mi] * 32 + ((gc ^ ((am[mi] >> 1) & 3)) * 8)];
                #pragma unroll
                for (int ni = 0; ni < 2; ni++)
                    bf[ni] = *(const v8s*)&bufB[bn[ni] * 32 + ((gc ^ ((bn[ni] >> 1) & 3)) * 8)];
                #pragma unroll
                for (int mi = 0; mi < 4; mi++)
                    #pragma unroll
                    for (int ni = 0; ni < 2; ni++)
                        acc[mi][ni] = __builtin_amdgcn_mfma_f32_32x32x16_bf16(af[mi], bf[ni], acc[mi][ni], 0, 0, 0);
            }
        }
        float scl = (n0 >= 1024) ? 0.125f : 1.0f;   // K section pre-scaled by D^-0.5
        #pragma unroll
        for (int mi = 0; mi < 4; mi++) {
            #pragma unroll
            for (int ni = 0; ni < 2; ni++) {
                int col = n0 + wn * 64 + ni * 32 + l32;
                #pragma unroll
                for (int r = 0; r < 16; r++) {
                    int row = m0 + wm * 128 + mi * 32 + (r & 3) + 8 * (r >> 2) + 4 * half;
                    Cout[(size_t)row * ldc + col] = f2b(acc[mi][ni][r] * scl);
                }
            }
        }
    } else {
        // ---------------- V branch: R2-exact 128x128, 3-stage, XCD stripe ------------
        constexpr int ABUF = 128 * 32;
        constexpr int BBUF = 128 * 32;
        unsigned short* lA = smem;               // 3*ABUF = 12288 shorts
        unsigned short* lB = smem + 3 * ABUF;    // 3*BBUF = 12288 shorts

        const unsigned short* Bv = Bt + (size_t)2048 * K;   // V rows of WqkvT
        int m0 = (xcd * 8 + (j & 7)) * 128;
        int n0 = (j >> 3) * 128;

        const unsigned short* gA[2];
        int offA[2];
        #pragma unroll
        for (int jj = 0; jj < 2; jj++) {
            int c = jj * 256 + tid;
            int row = c >> 2;
            int col8 = ((c & 3) ^ ((row >> 1) & 3)) * 8;
            gA[jj] = A + (size_t)(m0 + row) * K + col8;
            offA[jj] = (jj * 256 + w * 64) * 16;
        }
        const unsigned short* gB[2];
        int offB[2];
        #pragma unroll
        for (int jj = 0; jj < 2; jj++) {
            int c = jj * 256 + tid;
            int row = c >> 2;
            int col8 = ((c & 3) ^ ((row >> 1) & 3)) * 8;
            gB[jj] = Bv + (size_t)(n0 + row) * K + col8;
            offB[jj] = (jj * 256 + w * 64) * 16;
        }

        int am[2], bn[2];
        #pragma unroll
        for (int mi = 0; mi < 2; mi++) am[mi] = wm * 64 + mi * 32 + l32;
        #pragma unroll
        for (int ni = 0; ni < 2; ni++) bn[ni] = wn * 64 + ni * 32 + l32;

        v16f acc[2][2];
        #pragma unroll
        for (int mi = 0; mi < 2; mi++)
            #pragma unroll
            for (int ni = 0; ni < 2; ni++)
                #pragma unroll
                for (int r = 0; r < 16; r++) acc[mi][ni][r] = 0.f;

        int kt = K >> 5;
        #pragma unroll
        for (int jj = 0; jj < 2; jj++) GLOAD16(gA[jj], (char*)lA + offA[jj]);
        #pragma unroll
        for (int jj = 0; jj < 2; jj++) GLOAD16(gB[jj], (char*)lB + offB[jj]);
        #pragma unroll
        for (int jj = 0; jj < 2; jj++) GLOAD16(gA[jj] + 32, (char*)(lA + ABUF) + offA[jj]);
        #pragma unroll
        for (int jj = 0; jj < 2; jj++) GLOAD16(gB[jj] + 32, (char*)(lB + BBUF) + offB[jj]);

        int cur = 0;
        for (int it = 0; it < kt; it++) {
            int nx2 = cur + 2; if (nx2 >= 3) nx2 -= 3;
            __asm__ volatile("s_waitcnt vmcnt(4)" ::: "memory");
            __asm__ volatile("s_barrier" ::: "memory");
            {
                int kn = ((it + 2 < kt) ? it + 2 : kt - 1) << 5;
                #pragma unroll
                for (int jj = 0; jj < 2; jj++) GLOAD16(gA[jj] + kn, (char*)(lA + nx2 * ABUF) + offA[jj]);
                #pragma unroll
                for (int jj = 0; jj < 2; jj++) GLOAD16(gB[jj] + kn, (char*)(lB + nx2 * BBUF) + offB[jj]);
            }
            const unsigned short* bufA = lA + cur * ABUF;
            const unsigned short* bufB = lB + cur * BBUF;
            #pragma unroll
            for (int step = 0; step < 2; step++) {
                int gch = step * 2 + half;
                v8s af[2], bf[2];
                #pragma unroll
                for (int mi = 0; mi < 2; mi++)
                    af[mi] = *(const v8s*)&bufA[am[mi] * 32 + ((gch ^ ((am[mi] >> 1) & 3)) * 8)];
                #pragma unroll
                for (int ni = 0; ni < 2; ni++)
                    bf[ni] = *(const v8s*)&bufB[bn[ni] * 32 + ((gch ^ ((bn[ni] >> 1) & 3)) * 8)];
                #pragma unroll
                for (int mi = 0; mi < 2; mi++)
                    #pragma unroll
                    for (int ni = 0; ni < 2; ni++)
                        acc[mi][ni] = __builtin_amdgcn_mfma_f32_32x32x16_bf16(af[mi], bf[ni], acc[mi][ni], 0, 0, 0);
            }
            cur = cur + 1; if (cur >= 3) cur -= 3;
        }
        // epilogue: transpose 128(t) x 128(h*64+d) tile -> Vt[b,h,d,t]; 2 passes of 64 cols
        unsigned short* sT = lA;                 // 64 x 136 staging (reuse, 17.4 KB)
        int bB = m0 >> 10;
        int t0 = m0 & 1023;
        #pragma unroll
        for (int p = 0; p < 2; p++) {
            __syncthreads();
            if (wn == p) {
                #pragma unroll
                for (int mi = 0; mi < 2; mi++)
                    #pragma unroll
                    for (int ni = 0; ni < 2; ni++) {
                        int cl = ni * 32 + l32;
                        #pragma unroll
                        for (int r = 0; r < 16; r++) {
                            int rowl = wm * 64 + mi * 32 + (r & 3) + 8 * (r >> 2) + 4 * half;
                            sT[cl * 136 + rowl] = f2b(acc[mi][ni][r]);
                        }
                    }
            }
            __syncthreads();
            #pragma unroll
            for (int jj = 0; jj < 4; jj++) {
                int c = jj * 256 + tid;
                int cl = c >> 4, ch = c & 15;    // 64 cols x 16 v8s-chunks of 128 rows
                int vcol = n0 + p * 64 + cl;     // = h*64 + d
                int hh = vcol >> 6, dd = vcol & 63;
                *(v8s*)&Vt[(((size_t)bB * 16 + hh) * 64 + dd) * T_ + t0 + ch * 8] =
                    *(const v8s*)&sT[cl * 136 + ch * 8];
            }
        }
    }
}

// ---------------- GEMM proj (unchanged): 128x128, 3-stage pipeline, XCD stripe ------
__global__ __launch_bounds__(256, 3) void gemm_proj(const unsigned short* __restrict__ A,
                                                    const unsigned short* __restrict__ Bt,
                                                    float* __restrict__ Cout,
                                                    const float* __restrict__ bias,
                                                    int M, int N, int K) {
    constexpr int ABUF = 128 * 32;
    constexpr int BBUF = 128 * 32;
    __shared__ unsigned short lA[3 * ABUF];
    __shared__ unsigned short lB[3 * BBUF];

    int tid = threadIdx.x;
    int lane = tid & 63, w = tid >> 6;
    int half = lane >> 5, l32 = lane & 31;
    int wm = w >> 1, wn = w & 1;

    int g = blockIdx.x;
    int nbm = M / 128;
    int stripe = nbm >> 3;
    int xcd = g & 7, s = g >> 3;
    int m0 = (xcd * stripe + (s % stripe)) * 128;
    int n0 = (s / stripe) * 128;

    const unsigned short* gA[2];
    int offA[2];
    #pragma unroll
    for (int j = 0; j < 2; j++) {
        int c = j * 256 + tid;
        int row = c >> 2;
        int col8 = ((c & 3) ^ ((row >> 1) & 3)) * 8;
        gA[j] = A + (size_t)(m0 + row) * K + col8;
        offA[j] = (j * 256 + w * 64) * 16;
    }
    const unsigned short* gB[2];
    int offB[2];
    #pragma unroll
    for (int j = 0; j < 2; j++) {
        int c = j * 256 + tid;
        int row = c >> 2;
        int col8 = ((c & 3) ^ ((row >> 1) & 3)) * 8;
        gB[j] = Bt + (size_t)(n0 + row) * K + col8;
        offB[j] = (j * 256 + w * 64) * 16;
    }

    int am[2], bn[2];
    #pragma unroll
    for (int mi = 0; mi < 2; mi++) am[mi] = wm * 64 + mi * 32 + l32;
    #pragma unroll
    for (int ni = 0; ni < 2; ni++) bn[ni] = wn * 64 + ni * 32 + l32;

    v16f acc[2][2];
    #pragma unroll
    for (int mi = 0; mi < 2; mi++)
        #pragma unroll
        for (int ni = 0; ni < 2; ni++)
            #pragma unroll
            for (int r = 0; r < 16; r++) acc[mi][ni][r] = 0.f;

    int kt = K >> 5;
    #pragma unroll
    for (int j = 0; j < 2; j++) GLOAD16(gA[j], (char*)lA + offA[j]);
    #pragma unroll
    for (int j = 0; j < 2; j++) GLOAD16(gB[j], (char*)lB + offB[j]);
    #pragma unroll
    for (int j = 0; j < 2; j++) GLOAD16(gA[j] + 32, (char*)(lA + ABUF) + offA[j]);
    #pragma unroll
    for (int j = 0; j < 2; j++) GLOAD16(gB[j] + 32, (char*)(lB + BBUF) + offB[j]);

    int cur = 0;
    for (int it = 0; it < kt; it++) {
        int nx2 = cur + 2; if (nx2 >= 3) nx2 -= 3;
        __asm__ volatile("s_waitcnt vmcnt(4)" ::: "memory");
        __asm__ volatile("s_barrier" ::: "memory");
        {
            int kn = ((it + 2 < kt) ? it + 2 : kt - 1) << 5;
            #pragma unroll
            for (int j = 0; j < 2; j++) GLOAD16(gA[j] + kn, (char*)(lA + nx2 * ABUF) + offA[j]);
            #pragma unroll
            for (int j = 0; j < 2; j++) GLOAD16(gB[j] + kn, (char*)(lB + nx2 * BBUF) + offB[j]);
        }
        const unsigned short* bufA = lA + cur * ABUF;
        const unsigned short* bufB = lB + cur * BBUF;
        #pragma unroll
        for (int step = 0; step < 2; step++) {
            int gch = step * 2 + half;
            v8s af[2], bf[2];
            #pragma unroll
            for (int mi = 0; mi < 2; mi++)
                af[mi] = *(const v8s*)&bufA[am[mi] * 32 + ((gch ^ ((am[mi] >> 1) & 3)) * 8)];
            #pragma unroll
            for (int ni = 0; ni < 2; ni++)
                bf[ni] = *(const v8s*)&bufB[bn[ni] * 32 + ((gch ^ ((bn[ni] >> 1) & 3)) * 8)];
            #pragma unroll
            for (int mi = 0; mi < 2; mi++)
                #pragma unroll
                for (int ni = 0; ni < 2; ni++)
                    acc[mi][ni] = __builtin_amdgcn_mfma_f32_32x32x16_bf16(af[mi], bf[ni], acc[mi][ni], 0, 0, 0);
        }
        cur = cur + 1; if (cur >= 3) cur -= 3;
    }
    #pragma unroll
    for (int mi = 0; mi < 2; mi++) {
        #pragma unroll
        for (int ni = 0; ni < 2; ni++) {
            int col = n0 + wn * 64 + ni * 32 + l32;
            #pragma unroll
            for (int r = 0; r < 16; r++) {
                int row = m0 + wm * 64 + mi * 32 + (r & 3) + 8 * (r >> 2) + 4 * half;
                Cout[(size_t)row * N + col] = acc[mi][ni][r] + bias[col];
            }
        }
    }
}

// ---------------- Flash attention v7: 128-row q blocks (32 rows/warp) ------------------
// Halves tile-iterations vs v6 (9216 vs 17408): each K/V tile load + barrier is amortized
// over 2x the MFMA work. Same 32 KB LDS, same single vmcnt(0)+barrier per tile, same
// V-prefetch. Causal: ntiles = 2*qt+2, diag mask over last TWO tiles (R0-verified layout).
__global__ __launch_bounds__(256) void attn_kernel(const unsigned short* __restrict__ QKV,
                                                   const unsigned short* __restrict__ Vt,
                                                   unsigned short* __restrict__ Ob) {
    int bh = blockIdx.x;
    int qt = 7 - blockIdx.y;      // longest blocks dispatched first
    int b = bh >> 4, h = bh & 15;
    int tid = threadIdx.x, lane = tid & 63, w = tid >> 6;
    int quad = lane >> 4, l16 = lane & 15;
    int qg0 = qt * 128 + w * 32;  // each warp owns 32 q-rows

    __shared__ unsigned short lK[2][2][64][32];   // [buf][dhalf][s][32] 16 KB
    __shared__ unsigned short lV[2][2][64][32];   // [buf][shalf][d][32] 16 KB

    v8s aq[2][2];
    #pragma unroll
    for (int st = 0; st < 2; st++) {
        const unsigned short* qp = QKV + (size_t)(b * T_ + qg0 + st * 16 + l16) * QKVLD + h * 64;
        aq[st][0] = *(const v8s*)(qp + quad * 8);
        aq[st][1] = *(const v8s*)(qp + 32 + quad * 8);
    }

    const unsigned short* gK[2];
    const unsigned short* gV[2];
    int ldsOff[2];
    #pragma unroll
    for (int j = 0; j < 2; j++) {
        int c = j * 256 + tid;
        int halfp = c >> 8, row = (c >> 2) & 63;
        int col8 = ((c & 3) ^ ((row >> 1) & 3)) * 8;
        gK[j] = QKV + (size_t)(b * T_ + row) * QKVLD + 1024 + h * 64 + halfp * 32 + col8;
        gV[j] = Vt + ((size_t)bh * 64 + row) * T_ + halfp * 32 + col8;
        ldsOff[j] = (j * 256 + w * 64) * 16;
    }
    int rcol = (quad ^ ((l16 >> 1) & 3)) * 8;

    v4f accO[2][4];
    float lsum[2] = {0.f, 0.f};
    #pragma unroll
    for (int st = 0; st < 2; st++)
        #pragma unroll
        for (int i = 0; i < 4; i++) accO[st][i] = (v4f){0.f, 0.f, 0.f, 0.f};

    int ntiles = 2 * qt + 2;

    // prologue: K[0], V[0] -> buf 0
    #pragma unroll
    for (int j = 0; j < 2; j++) GLOAD16(gK[j], (char*)&lK[0][0][0][0] + ldsOff[j]);
    #pragma unroll
    for (int j = 0; j < 2; j++) GLOAD16(gV[j], (char*)&lV[0][0][0][0] + ldsOff[j]);

    for (int it = 0; it < ntiles; it++) {
        int cur = it & 1, nxt = cur ^ 1;
        int s0 = it * 64;
        __asm__ volatile("s_waitcnt vmcnt(0)" ::: "memory");
        __asm__ volatile("s_barrier" ::: "memory");
        {
            int itn = (it + 1 < ntiles) ? it + 1 : it;
            size_t koff = (size_t)itn * 64 * QKVLD;
            #pragma unroll
            for (int j = 0; j < 2; j++)
                GLOAD16(gK[j] + koff, (char*)&lK[nxt][0][0][0] + ldsOff[j]);
            size_t voff = (size_t)itn * 64;
            #pragma unroll
            for (int j = 0; j < 2; j++)
                GLOAD16(gV[j] + voff, (char*)&lV[nxt][0][0][0] + ldsOff[j]);
        }
        bool diag = (it >= ntiles - 2);
        // QK^T (S-transposed: row = s, col = q) + immediate softmax per (st,nt)
        v4s pP[2][4];
        #pragma unroll
        for (int nt = 0; nt < 4; nt++) {
            v8s bk0 = *(const v8s*)&lK[cur][0][nt * 16 + l16][rcol];
            v8s bk1 = *(const v8s*)&lK[cur][1][nt * 16 + l16][rcol];
            #pragma unroll
            for (int st = 0; st < 2; st++) {
                v4f a = (v4f){0.f, 0.f, 0.f, 0.f};
                a = MFMA32(bk0, aq[st][0], a);
                a = MFMA32(bk1, aq[st][1], a);
                int qg = qg0 + st * 16 + l16;
                float p[4];
                #pragma unroll
                for (int r = 0; r < 4; r++) {
                    float e = __expf(a[r]);
                    if (diag) {
                        int sg = s0 + nt * 16 + quad * 4 + r;
                        e = (sg > qg) ? 0.f : e;
                    }
                    p[r] = e;
                    lsum[st] += e;
                }
                pP[st][nt] = pack4(p[0], p[1], p[2], p[3]);
            }
        }
        // PV from lV[cur] (prefetched last iteration); bv shared across both st
        #pragma unroll
        for (int kb = 0; kb < 4; kb++) {
            int sc_ = kb >> 1;
            int ccg = (kb & 1) * 2 + (quad >> 1);
            #pragma unroll
            for (int dt = 0; dt < 4; dt++) {
                int d = dt * 16 + l16;
                int ccp = ccg ^ ((l16 >> 1) & 3);
                v4s bv = *(const v4s*)&lV[cur][sc_][d][ccp * 8 + (quad & 1) * 4];
                accO[0][dt] = MFMA16(pP[0][kb], bv, accO[0][dt]);
                accO[1][dt] = MFMA16(pP[1][kb], bv, accO[1][dt]);
            }
        }
    }
    #pragma unroll
    for (int st = 0; st < 2; st++) {
        float ls = lsum[st];
        ls += __shfl_xor(ls, 16, 64);
        ls += __shfl_xor(ls, 32, 64);
        #pragma unroll
        for (int r = 0; r < 4; r++) {
            float lq = __shfl(ls, quad * 4 + r, 64);
            float inv = 1.0f / lq;
            int q = qg0 + st * 16 + quad * 4 + r;
            #pragma unroll
            for (int dt = 0; dt < 4; dt++) {
                int d = dt * 16 + l16;
                Ob[(size_t)(b * T_ + q) * (H_ * D_) + h * 64 + d] = f2b(accO[st][dt][r] * inv);
            }
        }
    }
}

extern "C" void kernel_launch(void* const* d_in, const int* in_sizes, int n_in,
                              void* d_out, int out_size, void* d_ws, size_t ws_size,
                              hipStream_t stream) {
    const float* x     = (const float*)d_in[0];
    const float* Wq    = (const float*)d_in[1];
    const float* Wk    = (const float*)d_in[2];
    const float* Wv    = (const float*)d_in[3];
    const float* Wproj = (const float*)d_in[4];
    const float* bproj = (const float*)d_in[5];
    float* out = (float*)d_out;

    char* ws = (char*)d_ws;
    unsigned short* xb     = (unsigned short*)ws;                          // 16 MB  [8192][1024]
    unsigned short* WqkvT  = (unsigned short*)(ws + 16777216);             // 6 MB   [3072][1024]
    unsigned short* WprojT = (unsigned short*)(ws + 23068672);             // 2 MB   [1024][1024]
    unsigned short* QKV    = (unsigned short*)(ws + 25165824);             // 48 MB  [8192][3072] (Q|K used)
    unsigned short* Vt     = (unsigned short*)(ws + 75497472);             // 16 MB  [B,H,D,T]
    unsigned short* Ob     = (unsigned short*)(ws + 92274688);             // 16 MB  [8192][1024]

    prep_kernel<<<dim3(9216), dim3(256), 0, stream>>>(x, Wq, Wk, Wv, Wproj, xb, WqkvT, WprojT);
    gemm_qkv<<<dim3(1024), dim3(256), 0, stream>>>(xb, WqkvT, QKV, Vt, 1024, QKVLD);
    attn_kernel<<<dim3(128, 8), dim3(256), 0, stream>>>(QKV, Vt, Ob);
    gemm_proj<<<dim3(512), dim3(256), 0, stream>>>(Ob, WprojT, out, bproj, 8192, 1024, 1024);
}